// Round 1
// baseline (1745.354 us; speedup 1.0000x reference)
//
#include <hip/hip_runtime.h>

// KarrasOptimalDenoiser: B=64, C*H*W=D=3072, N=50000.
// out[b] = softmax_n(-0.5*||x_b - Y_n||^2 / sigma_b^2) @ Y
// (per-row constants in log_p cancel in softmax and are dropped)
//
// Round 0: correct fp32 baseline.
//   A0: transpose X -> XT[k][b], compute x2[b]
//   A : scores sT[n][b] = -0.5*max(x2+y2-2*dot,0)*inv_var   (tiled fp32 GEMM)
//   B1/B2: online-softmax row stats (m[b], 1/l[b]) via 256 partials
//   C : out += w[b,n]*Y[n,d] over 32 n-chunks, unsafeAtomicAdd epilogue

#define BB 64
#define DD 3072
#define NN 50000
#define NSPAD 50048
#define TN 128
#define NCC 1568

// ---------------- A0: transpose X + ||x||^2 ----------------
__global__ __launch_bounds__(256) void xpose_kernel(const float* __restrict__ x,
                                                    float* __restrict__ XT,
                                                    float* __restrict__ x2g) {
  const int b = blockIdx.x;
  const int t = threadIdx.x;
  const float4* xr = (const float4*)(x + (size_t)b * DD);
  float ss = 0.f;
#pragma unroll
  for (int i = 0; i < 3; ++i) {
    int idx = t + i * 256;  // 768 float4 per row
    float4 v = xr[idx];
    int k = idx * 4;
    XT[(size_t)(k + 0) * BB + b] = v.x;
    XT[(size_t)(k + 1) * BB + b] = v.y;
    XT[(size_t)(k + 2) * BB + b] = v.z;
    XT[(size_t)(k + 3) * BB + b] = v.w;
    ss += v.x * v.x + v.y * v.y + v.z * v.z + v.w * v.w;
  }
#pragma unroll
  for (int off = 32; off > 0; off >>= 1) ss += __shfl_down(ss, off, 64);
  __shared__ float red[4];
  if ((t & 63) == 0) red[t >> 6] = ss;
  __syncthreads();
  if (t == 0) x2g[b] = red[0] + red[1] + red[2] + red[3];
}

// ---------------- A: score GEMM, stores transposed sT[n][b] ----------------
__global__ __launch_bounds__(256) void score_kernel(const float* __restrict__ Y,
                                                    const float* __restrict__ XT,
                                                    const float* __restrict__ x2g,
                                                    const float* __restrict__ sigma,
                                                    float* __restrict__ sT) {
  const int t = threadIdx.x;
  const int n0 = blockIdx.x * TN;
  __shared__ float Xs[32][64];        // [k][b]
  __shared__ float Ys[32][TN + 4];    // [k][n], +4 pad keeps 16B align & banks spread
  __shared__ float y2tmp[2][TN];

  float acc[4][8] = {};
  const int b0 = (t & 15) * 4;   // 4 consecutive b
  const int nf = (t >> 4) * 8;   // 8 consecutive n
  const int ny = t & 127;        // y2 ownership
  const int kh = t >> 7;
  float y2a = 0.f;

  const int xk = t >> 4;          // 0..15
  const int xbq = (t & 15) * 4;
  const int yn = t >> 3;          // 0..31
  const int ykq = (t & 7) * 4;

  for (int kt = 0; kt < DD; kt += 32) {
#pragma unroll
    for (int j = 0; j < 2; ++j) {
      int k = xk + j * 16;
      *(float4*)&Xs[k][xbq] = *(const float4*)&XT[(size_t)(kt + k) * BB + xbq];
    }
#pragma unroll
    for (int j = 0; j < 4; ++j) {
      int n = yn + j * 32;
      int ng = n0 + n;
      float4 v = make_float4(0.f, 0.f, 0.f, 0.f);
      if (ng < NN) v = *(const float4*)&Y[(size_t)ng * DD + kt + ykq];
      Ys[ykq + 0][n] = v.x;
      Ys[ykq + 1][n] = v.y;
      Ys[ykq + 2][n] = v.z;
      Ys[ykq + 3][n] = v.w;
    }
    __syncthreads();
    // ||y||^2 partials (cheap: 16 FMA vs 1024 FMA main loop)
#pragma unroll
    for (int kk = 0; kk < 16; ++kk) {
      float v = Ys[kh * 16 + kk][ny];
      y2a = fmaf(v, v, y2a);
    }
    // main 4b x 8n register tile
#pragma unroll
    for (int k = 0; k < 32; ++k) {
      float4 a = *(const float4*)&Xs[k][b0];
      float4 p = *(const float4*)&Ys[k][nf];
      float4 q = *(const float4*)&Ys[k][nf + 4];
      float av[4] = {a.x, a.y, a.z, a.w};
      float yv[8] = {p.x, p.y, p.z, p.w, q.x, q.y, q.z, q.w};
#pragma unroll
      for (int bi = 0; bi < 4; ++bi)
#pragma unroll
        for (int nj = 0; nj < 8; ++nj)
          acc[bi][nj] = fmaf(av[bi], yv[nj], acc[bi][nj]);
    }
    __syncthreads();
  }
  y2tmp[kh][ny] = y2a;
  __syncthreads();

  float4 xx = *(const float4*)&x2g[b0];
  float4 sg = *(const float4*)&sigma[b0];
  float iv[4] = {1.f / (sg.x * sg.x), 1.f / (sg.y * sg.y),
                 1.f / (sg.z * sg.z), 1.f / (sg.w * sg.w)};
  float xv[4] = {xx.x, xx.y, xx.z, xx.w};
#pragma unroll
  for (int nj = 0; nj < 8; ++nj) {
    int n = nf + nj;
    float y2v = y2tmp[0][n] + y2tmp[1][n];
    float o[4];
#pragma unroll
    for (int bi = 0; bi < 4; ++bi) {
      float d2 = xv[bi] + y2v - 2.f * acc[bi][nj];
      d2 = fmaxf(d2, 0.f);
      o[bi] = -0.5f * d2 * iv[bi];
    }
    // n0+n <= 50047 < NSPAD; rows >= NN are junk but never read
    *(float4*)&sT[(size_t)(n0 + n) * BB + b0] = make_float4(o[0], o[1], o[2], o[3]);
  }
}

// ---------------- B1: per-block online softmax partials ----------------
__global__ __launch_bounds__(256) void softstat1_kernel(const float* __restrict__ sT,
                                                        float* __restrict__ pM,
                                                        float* __restrict__ pL) {
  const int t = threadIdx.x;
  const int b = t & 63;
  const int g = t >> 6;
  float m = -3.402823466e38f, l = 0.f;
  for (int n = blockIdx.x * 4 + g; n < NN; n += 1024) {
    float s = sT[(size_t)n * BB + b];
    if (s > m) {
      l = fmaf(l, __expf(m - s), 1.f);
      m = s;
    } else {
      l += __expf(s - m);
    }
  }
  __shared__ float sm[256], sl[256];
  sm[t] = m;
  sl[t] = l;
  __syncthreads();
  if (g == 0) {
#pragma unroll
    for (int j = 1; j < 4; ++j) {
      float m2 = sm[j * 64 + b], l2 = sl[j * 64 + b];
      if (m2 > m) {
        l = fmaf(l, __expf(m - m2), l2);
        m = m2;
      } else {
        l = fmaf(l2, __expf(m2 - m), l);
      }
    }
    pM[blockIdx.x * 64 + b] = m;
    pL[blockIdx.x * 64 + b] = l;
  }
}

// ---------------- B2: combine 256 partials -> m[b], 1/l[b] ----------------
__global__ void softstat2_kernel(const float* __restrict__ pM,
                                 const float* __restrict__ pL,
                                 float* __restrict__ mbuf,
                                 float* __restrict__ rlb) {
  const int b = threadIdx.x;  // 64 threads
  float m = -3.402823466e38f, l = 0.f;
  for (int i = 0; i < 256; ++i) {
    float m2 = pM[i * 64 + b], l2 = pL[i * 64 + b];
    if (m2 > m) {
      l = fmaf(l, __expf(m - m2), l2);
      m = m2;
    } else {
      l = fmaf(l2, __expf(m2 - m), l);
    }
  }
  mbuf[b] = m;
  rlb[b] = 1.f / l;
}

// ---------------- C: out[b,d] += sum_n w[b,n] * Y[n,d] ----------------
__global__ __launch_bounds__(256) void wsum_kernel(const float* __restrict__ Y,
                                                   const float* __restrict__ sT,
                                                   const float* __restrict__ mbuf,
                                                   const float* __restrict__ rlb,
                                                   float* __restrict__ out) {
  const int t = threadIdx.x;
  const int dt0 = (blockIdx.x % 24) * 128;  // 24 d-tiles of 128
  const int c = blockIdx.x / 24;            // 32 n-chunks
  const int nstart = c * NCC;
  const int nend = min(nstart + NCC, NN);

  __shared__ float Ws[32][64];    // [n][b] weights
  __shared__ float Ys2[32][128];  // [n][d] natural layout

  float acc[4][8] = {};
  const int b0 = (t & 15) * 4;
  const int d0 = (t >> 4) * 8;

  const int wn = t >> 4;          // 0..15
  const int wbq = (t & 15) * 4;
  const int yn = t >> 5;          // 0..7
  const int ydq = (t & 31) * 4;

  const float4 m4 = *(const float4*)&mbuf[wbq];
  const float4 r4 = *(const float4*)&rlb[wbq];

  for (int nt = nstart; nt < nend; nt += 32) {
#pragma unroll
    for (int j = 0; j < 2; ++j) {
      int n = nt + wn + j * 16;
      float4 w = make_float4(0.f, 0.f, 0.f, 0.f);
      if (n < nend) {
        float4 s = *(const float4*)&sT[(size_t)n * BB + wbq];
        w.x = __expf(s.x - m4.x) * r4.x;
        w.y = __expf(s.y - m4.y) * r4.y;
        w.z = __expf(s.z - m4.z) * r4.z;
        w.w = __expf(s.w - m4.w) * r4.w;
      }
      *(float4*)&Ws[wn + j * 16][wbq] = w;
    }
#pragma unroll
    for (int j = 0; j < 4; ++j) {
      int n = nt + yn + j * 8;
      float4 v = make_float4(0.f, 0.f, 0.f, 0.f);
      if (n < nend) v = *(const float4*)&Y[(size_t)n * DD + dt0 + ydq];
      *(float4*)&Ys2[yn + j * 8][ydq] = v;
    }
    __syncthreads();
#pragma unroll
    for (int k = 0; k < 32; ++k) {
      float4 wb = *(const float4*)&Ws[k][b0];
      float4 p = *(const float4*)&Ys2[k][d0];
      float4 q = *(const float4*)&Ys2[k][d0 + 4];
      float wv[4] = {wb.x, wb.y, wb.z, wb.w};
      float yv[8] = {p.x, p.y, p.z, p.w, q.x, q.y, q.z, q.w};
#pragma unroll
      for (int bi = 0; bi < 4; ++bi)
#pragma unroll
        for (int dj = 0; dj < 8; ++dj)
          acc[bi][dj] = fmaf(wv[bi], yv[dj], acc[bi][dj]);
    }
    __syncthreads();
  }
#pragma unroll
  for (int bi = 0; bi < 4; ++bi)
#pragma unroll
    for (int dj = 0; dj < 8; ++dj)
      unsafeAtomicAdd(&out[(size_t)(b0 + bi) * DD + dt0 + d0 + dj], acc[bi][dj]);
}

extern "C" void kernel_launch(void* const* d_in, const int* in_sizes, int n_in,
                              void* d_out, int out_size, void* d_ws, size_t ws_size,
                              hipStream_t stream) {
  const float* x = (const float*)d_in[0];      // [64,3,32,32]
  const float* sigma = (const float*)d_in[1];  // [64]
  const float* Y = (const float*)d_in[2];      // [50000,3,32,32]
  float* out = (float*)d_out;

  float* ws = (float*)d_ws;
  float* sT = ws;                               // NSPAD*64
  float* XT = sT + (size_t)NSPAD * BB;          // 3072*64
  float* x2g = XT + (size_t)DD * BB;            // 64
  float* pM = x2g + 64;                         // 256*64
  float* pL = pM + 256 * 64;                    // 256*64
  float* mbuf = pL + 256 * 64;                  // 64
  float* rlb = mbuf + 64;                       // 64
  // total ws use: ~13.8 MB

  hipMemsetAsync(d_out, 0, (size_t)out_size * sizeof(float), stream);
  hipLaunchKernelGGL(xpose_kernel, dim3(BB), dim3(256), 0, stream, x, XT, x2g);
  hipLaunchKernelGGL(score_kernel, dim3((NN + TN - 1) / TN), dim3(256), 0, stream,
                     Y, XT, x2g, sigma, sT);
  hipLaunchKernelGGL(softstat1_kernel, dim3(256), dim3(256), 0, stream, sT, pM, pL);
  hipLaunchKernelGGL(softstat2_kernel, dim3(1), dim3(64), 0, stream, pM, pL, mbuf, rlb);
  hipLaunchKernelGGL(wsum_kernel, dim3(24 * 32), dim3(256), 0, stream,
                     Y, sT, mbuf, rlb, out);
}

// Round 2
// 1139.458 us; speedup vs baseline: 1.5317x; 1.5317x over previous
//
#include <hip/hip_runtime.h>

// KarrasOptimalDenoiser: B=64, D=3072, N=50000.
// out[b] = softmax_n(-0.5*||x_b - Y_n||^2 / sigma_b^2) @ Y
// Round 1: both GEMMs on MFMA bf16 hi/lo split (3-term, lo*lo dropped).
//   xpose   : X -> A-fragment-packed bf16 hi/lo (XhiP/XloP), x2[b], inv_var[b]
//   score   : sT[n][b] via mfma 16x16x32, Y streamed fp32->bf16 in-register
//   softstat: online-softmax partials with 4-way ILP, then combine -> m[b], 1/l[b]
//   wprep   : w = exp(s-m)/l packed to A-frag bf16 hi/lo (WH/WL)
//   wsum    : out += w @ Y via mfma, atomicAdd epilogue over 56 n-chunks

#define BB 64
#define DD 3072
#define NN 50000
#define NSPAD 50176    // 56*896, multiple of 64; rows >= NN zero-weighted
#define NGRP 384       // DD/8
#define SGRP 6272      // NSPAD/8
#define NCHK 896       // n per wsum chunk (28 k-steps)

typedef __attribute__((ext_vector_type(8))) short bf16x8;   // 8 bf16 = 4 VGPR
typedef __attribute__((ext_vector_type(4))) float f32x4;    // C/D frag

__device__ __forceinline__ unsigned short f2bf(float f) {   // fp32 -> bf16 RNE
  unsigned u = __float_as_uint(f);
  u += 0x7FFFu + ((u >> 16) & 1u);
  return (unsigned short)(u >> 16);
}
__device__ __forceinline__ float bf2f(unsigned short h) {
  return __uint_as_float(((unsigned)h) << 16);
}

// ---------------- xpose: pack X into A-frag layout [k/8][64b][8] ----------------
__global__ __launch_bounds__(256) void xpose_kernel(const float* __restrict__ x,
                                                    const float* __restrict__ sigma,
                                                    unsigned short* __restrict__ XhiP,
                                                    unsigned short* __restrict__ XloP,
                                                    float* __restrict__ x2g,
                                                    float* __restrict__ ivg) {
  const int b = blockIdx.x;
  const int t = threadIdx.x;
  const float4* xr = (const float4*)(x + (long)b * DD);
  float ss = 0.f;
#pragma unroll
  for (int i = 0; i < 3; ++i) {
    int idx = t + i * 256;        // 768 float4 per row
    float4 v = xr[idx];
    int grp = idx >> 1;
    int off = (idx & 1) * 4;      // k%8 in {0,4}
    ushort4 hh, ll;
    hh.x = f2bf(v.x); ll.x = f2bf(v.x - bf2f(hh.x));
    hh.y = f2bf(v.y); ll.y = f2bf(v.y - bf2f(hh.y));
    hh.z = f2bf(v.z); ll.z = f2bf(v.z - bf2f(hh.z));
    hh.w = f2bf(v.w); ll.w = f2bf(v.w - bf2f(hh.w));
    long o = ((long)grp * 64 + b) * 8 + off;
    *(ushort4*)(XhiP + o) = hh;
    *(ushort4*)(XloP + o) = ll;
    ss = fmaf(v.x, v.x, ss); ss = fmaf(v.y, v.y, ss);
    ss = fmaf(v.z, v.z, ss); ss = fmaf(v.w, v.w, ss);
  }
#pragma unroll
  for (int off = 32; off > 0; off >>= 1) ss += __shfl_down(ss, off, 64);
  __shared__ float red[4];
  if ((t & 63) == 0) red[t >> 6] = ss;
  __syncthreads();
  if (t == 0) {
    x2g[b] = red[0] + red[1] + red[2] + red[3];
    float sg = sigma[b];
    ivg[b] = 1.f / (sg * sg);
  }
}

// ---------------- score: sT[n][b] via MFMA ----------------
// block = 4 waves, wave w covers n in [blk*64 + w*16, +16), all 64 b (4 m-tiles)
__global__ __launch_bounds__(256) void score_kernel(const float* __restrict__ Y,
                                                    const unsigned short* __restrict__ XhiP,
                                                    const unsigned short* __restrict__ XloP,
                                                    const float* __restrict__ x2g,
                                                    const float* __restrict__ ivg,
                                                    float* __restrict__ sT) {
  const int t = threadIdx.x;
  const int w = t >> 6;
  const int l = t & 63;
  const int l15 = l & 15, q = l >> 4;
  const int n = blockIdx.x * 64 + w * 16 + l15;
  const long nc = (n < NN) ? n : (NN - 1);          // clamp: junk rows zero-weighted later
  const float* yrow = Y + nc * (long)DD + q * 8;

  __shared__ float x2s[64], ivs[64];
  __shared__ float tr[4][16][68];                    // per-wave transpose buffer
  if (t < 64) { x2s[t] = x2g[t]; ivs[t] = ivg[t]; }
  __syncthreads();

  f32x4 acc[4] = {};
  float y2 = 0.f;

  for (int kt = 0; kt < DD; kt += 32) {
    float4 b0 = *(const float4*)(yrow + kt);
    float4 b1 = *(const float4*)(yrow + kt + 4);
    const int grp = (kt >> 3) + q;
    const bf16x8* Ah = (const bf16x8*)XhiP + (long)grp * 64 + l15;
    const bf16x8* Al = (const bf16x8*)XloP + (long)grp * 64 + l15;
    bf16x8 a_h[4], a_l[4];
#pragma unroll
    for (int mt = 0; mt < 4; ++mt) { a_h[mt] = Ah[mt * 16]; a_l[mt] = Al[mt * 16]; }

    y2 = fmaf(b0.x, b0.x, y2); y2 = fmaf(b0.y, b0.y, y2);
    y2 = fmaf(b0.z, b0.z, y2); y2 = fmaf(b0.w, b0.w, y2);
    y2 = fmaf(b1.x, b1.x, y2); y2 = fmaf(b1.y, b1.y, y2);
    y2 = fmaf(b1.z, b1.z, y2); y2 = fmaf(b1.w, b1.w, y2);

    float fv[8] = {b0.x, b0.y, b0.z, b0.w, b1.x, b1.y, b1.z, b1.w};
    bf16x8 bh, bl;
#pragma unroll
    for (int j = 0; j < 8; ++j) {
      unsigned short h = f2bf(fv[j]);
      bh[j] = (short)h;
      bl[j] = (short)f2bf(fv[j] - bf2f(h));
    }
#pragma unroll
    for (int mt = 0; mt < 4; ++mt) {
      acc[mt] = __builtin_amdgcn_mfma_f32_16x16x32_bf16(a_h[mt], bh, acc[mt], 0, 0, 0);
      acc[mt] = __builtin_amdgcn_mfma_f32_16x16x32_bf16(a_h[mt], bl, acc[mt], 0, 0, 0);
      acc[mt] = __builtin_amdgcn_mfma_f32_16x16x32_bf16(a_l[mt], bh, acc[mt], 0, 0, 0);
    }
  }

  // y2 partials live per (row=l15, k-quarter=q): reduce over q
  y2 += __shfl_xor(y2, 16, 64);
  y2 += __shfl_xor(y2, 32, 64);

  // transform + stage to LDS [n-within-wave][b]
#pragma unroll
  for (int mt = 0; mt < 4; ++mt) {
#pragma unroll
    for (int r = 0; r < 4; ++r) {
      int b = mt * 16 + q * 4 + r;                   // C/D: row=q*4+r, col=l15
      float s = fminf(-0.5f * ivs[b] * (x2s[b] + y2 - 2.f * acc[mt][r]), 0.f);
      tr[w][l15][b] = s;
    }
  }
  __syncthreads();
  // coalesced write: lane l writes 64B of row (blk*64 + w*16 + l15)
  const long nrow = (long)blockIdx.x * 64 + w * 16 + l15;
  float* dst = sT + nrow * 64 + q * 16;
  const float* src = &tr[w][l15][q * 16];
  *(float4*)(dst + 0)  = *(const float4*)(src + 0);
  *(float4*)(dst + 4)  = *(const float4*)(src + 4);
  *(float4*)(dst + 8)  = *(const float4*)(src + 8);
  *(float4*)(dst + 12) = *(const float4*)(src + 12);
}

// ---------------- softstat1: 4-way-ILP online partials ----------------
__global__ __launch_bounds__(256) void softstat1_kernel(const float* __restrict__ sT,
                                                        float* __restrict__ pM,
                                                        float* __restrict__ pL) {
  const int t = threadIdx.x;
  const int b = t & 63;
  const int g = t >> 6;
  const int slot = blockIdx.x * 4 + g;   // 1024 slots over n
  float m[4], l[4];
#pragma unroll
  for (int u = 0; u < 4; ++u) { m[u] = -3.402823466e38f; l[u] = 0.f; }
  for (int j = 0; j < 52; j += 4) {
    float sv[4];
#pragma unroll
    for (int u = 0; u < 4; ++u) {
      int n = slot + (j + u) * 1024;
      sv[u] = (n < NN) ? sT[(long)n * 64 + b] : -3.402823466e38f;
    }
#pragma unroll
    for (int u = 0; u < 4; ++u) {
      float nm = fmaxf(m[u], sv[u]);
      l[u] = fmaf(l[u], __expf(m[u] - nm), __expf(sv[u] - nm));
      m[u] = nm;
    }
  }
#pragma unroll
  for (int u = 1; u < 4; ++u) {
    float nm = fmaxf(m[0], m[u]);
    l[0] = fmaf(l[0], __expf(m[0] - nm), l[u] * __expf(m[u] - nm));
    m[0] = nm;
  }
  __shared__ float sm[256], sl[256];
  sm[t] = m[0]; sl[t] = l[0];
  __syncthreads();
  if (g == 0) {
    float mm = m[0], ll = l[0];
#pragma unroll
    for (int j = 1; j < 4; ++j) {
      float m2 = sm[j * 64 + b], l2 = sl[j * 64 + b];
      float nm = fmaxf(mm, m2);
      ll = fmaf(ll, __expf(mm - nm), l2 * __expf(m2 - nm));
      mm = nm;
    }
    pM[blockIdx.x * 64 + b] = mm;
    pL[blockIdx.x * 64 + b] = ll;
  }
}

// ---------------- softstat2: combine 256 partials ----------------
__global__ __launch_bounds__(256) void softstat2_kernel(const float* __restrict__ pM,
                                                        const float* __restrict__ pL,
                                                        float* __restrict__ mg,
                                                        float* __restrict__ rlg) {
  const int t = threadIdx.x;
  const int b = t & 63;
  const int g = t >> 6;
  float m = -3.402823466e38f, l = 0.f;
  for (int i = g; i < 256; i += 4) {
    float m2 = pM[i * 64 + b], l2 = pL[i * 64 + b];
    float nm = fmaxf(m, m2);
    l = fmaf(l, __expf(m - nm), l2 * __expf(m2 - nm));
    m = nm;
  }
  __shared__ float sm[256], sl[256];
  sm[t] = m; sl[t] = l;
  __syncthreads();
  if (g == 0) {
#pragma unroll
    for (int j = 1; j < 4; ++j) {
      float m2 = sm[j * 64 + b], l2 = sl[j * 64 + b];
      float nm = fmaxf(m, m2);
      l = fmaf(l, __expf(m - nm), l2 * __expf(m2 - nm));
      m = nm;
    }
    mg[b] = m;
    rlg[b] = 1.f / l;
  }
}

// ---------------- wprep: w -> A-frag bf16 hi/lo [n/8][64b][8] ----------------
__global__ __launch_bounds__(256) void wprep_kernel(const float* __restrict__ sT,
                                                    const float* __restrict__ mg,
                                                    const float* __restrict__ rlg,
                                                    unsigned short* __restrict__ WH,
                                                    unsigned short* __restrict__ WL) {
  const int t = threadIdx.x;
  const int b = t & 63;
  const int grp = blockIdx.x * 4 + (t >> 6);     // grid 1568 -> grp < 6272
  const float mb = mg[b], rb = rlg[b];
  bf16x8 H, L;
#pragma unroll
  for (int j = 0; j < 8; ++j) {
    int n = grp * 8 + j;
    float s = sT[(long)n * 64 + b];
    float wv = (n < NN) ? __expf(s - mb) * rb : 0.f;   // zero out pad rows (incl. NaN poison)
    unsigned short h = f2bf(wv);
    H[j] = (short)h;
    L[j] = (short)f2bf(wv - bf2f(h));
  }
  *((bf16x8*)WH + (long)grp * 64 + b) = H;
  *((bf16x8*)WL + (long)grp * 64 + b) = L;
}

// ---------------- wsum: out[b][d] += w @ Y via MFMA ----------------
// block = 4 waves; wave w covers d in [dblk*128 + w*32, +32) (2 d-tiles), all 64 b
__global__ __launch_bounds__(256) void wsum_kernel(const float* __restrict__ Y,
                                                   const unsigned short* __restrict__ WH,
                                                   const unsigned short* __restrict__ WL,
                                                   float* __restrict__ out) {
  const int t = threadIdx.x;
  const int w = t >> 6;
  const int l = t & 63;
  const int l15 = l & 15, q = l >> 4;
  const int dblk = blockIdx.x % 24;
  const int c = blockIdx.x / 24;                  // 56 n-chunks
  const int d0 = dblk * 128 + w * 32 + l15;
  const int nstart = c * NCHK;

  f32x4 acc[4][2] = {};

  for (int k0 = nstart; k0 < nstart + NCHK; k0 += 32) {
    const int grp = (k0 >> 3) + q;
    const bf16x8* Ah = (const bf16x8*)WH + (long)grp * 64 + l15;
    const bf16x8* Al = (const bf16x8*)WL + (long)grp * 64 + l15;
    bf16x8 wh[4], wl[4];
#pragma unroll
    for (int mt = 0; mt < 4; ++mt) { wh[mt] = Ah[mt * 16]; wl[mt] = Al[mt * 16]; }

    const int rbase = k0 + q * 8;
    float f0[8], f1[8];
#pragma unroll
    for (int j = 0; j < 8; ++j) {
      long r = rbase + j;
      r = (r < NN) ? r : (NN - 1);                // clamped; weight is 0 there
      const float* yp = Y + r * (long)DD + d0;
      f0[j] = yp[0];
      f1[j] = yp[16];
    }
    bf16x8 yh0, yl0, yh1, yl1;
#pragma unroll
    for (int j = 0; j < 8; ++j) {
      unsigned short h0 = f2bf(f0[j]);
      yh0[j] = (short)h0; yl0[j] = (short)f2bf(f0[j] - bf2f(h0));
      unsigned short h1 = f2bf(f1[j]);
      yh1[j] = (short)h1; yl1[j] = (short)f2bf(f1[j] - bf2f(h1));
    }
#pragma unroll
    for (int mt = 0; mt < 4; ++mt) {
      acc[mt][0] = __builtin_amdgcn_mfma_f32_16x16x32_bf16(wh[mt], yh0, acc[mt][0], 0, 0, 0);
      acc[mt][0] = __builtin_amdgcn_mfma_f32_16x16x32_bf16(wh[mt], yl0, acc[mt][0], 0, 0, 0);
      acc[mt][0] = __builtin_amdgcn_mfma_f32_16x16x32_bf16(wl[mt], yh0, acc[mt][0], 0, 0, 0);
      acc[mt][1] = __builtin_amdgcn_mfma_f32_16x16x32_bf16(wh[mt], yh1, acc[mt][1], 0, 0, 0);
      acc[mt][1] = __builtin_amdgcn_mfma_f32_16x16x32_bf16(wh[mt], yl1, acc[mt][1], 0, 0, 0);
      acc[mt][1] = __builtin_amdgcn_mfma_f32_16x16x32_bf16(wl[mt], yh1, acc[mt][1], 0, 0, 0);
    }
  }

#pragma unroll
  for (int mt = 0; mt < 4; ++mt)
#pragma unroll
    for (int dt = 0; dt < 2; ++dt)
#pragma unroll
      for (int r = 0; r < 4; ++r) {
        int b = mt * 16 + q * 4 + r;
        unsafeAtomicAdd(&out[(long)b * DD + d0 + dt * 16], acc[mt][dt][r]);
      }
}

extern "C" void kernel_launch(void* const* d_in, const int* in_sizes, int n_in,
                              void* d_out, int out_size, void* d_ws, size_t ws_size,
                              hipStream_t stream) {
  const float* x = (const float*)d_in[0];      // [64,3,32,32]
  const float* sigma = (const float*)d_in[1];  // [64]
  const float* Y = (const float*)d_in[2];      // [50000,3,32,32]
  float* out = (float*)d_out;

  char* p = (char*)d_ws;
  float* sT = (float*)p;            p += (long)NSPAD * 64 * 4;   // 12.85 MB
  unsigned short* WH = (unsigned short*)p; p += (long)NSPAD * 64 * 2;  // 6.4 MB
  unsigned short* WL = (unsigned short*)p; p += (long)NSPAD * 64 * 2;  // 6.4 MB
  unsigned short* XhiP = (unsigned short*)p; p += (long)NGRP * 64 * 8 * 2;  // 384 KB
  unsigned short* XloP = (unsigned short*)p; p += (long)NGRP * 64 * 8 * 2;  // 384 KB
  float* x2g = (float*)p; p += 64 * 4;
  float* ivg = (float*)p; p += 64 * 4;
  float* mg  = (float*)p; p += 64 * 4;
  float* rlg = (float*)p; p += 64 * 4;
  float* pM  = (float*)p; p += 256 * 64 * 4;
  float* pL  = (float*)p; p += 256 * 64 * 4;
  // total ws use ~26.7 MB

  hipMemsetAsync(d_out, 0, (size_t)out_size * sizeof(float), stream);
  hipLaunchKernelGGL(xpose_kernel, dim3(BB), dim3(256), 0, stream,
                     x, sigma, XhiP, XloP, x2g, ivg);
  hipLaunchKernelGGL(score_kernel, dim3(782), dim3(256), 0, stream,
                     Y, XhiP, XloP, x2g, ivg, sT);
  hipLaunchKernelGGL(softstat1_kernel, dim3(256), dim3(256), 0, stream, sT, pM, pL);
  hipLaunchKernelGGL(softstat2_kernel, dim3(1), dim3(256), 0, stream, pM, pL, mg, rlg);
  hipLaunchKernelGGL(wprep_kernel, dim3(SGRP / 4), dim3(256), 0, stream,
                     sT, mg, rlg, WH, WL);
  hipLaunchKernelGGL(wsum_kernel, dim3(24 * 56), dim3(256), 0, stream,
                     Y, WH, WL, out);
}